// Round 5
// baseline (546.538 us; speedup 1.0000x reference)
//
#include <hip/hip_runtime.h>
#include <math.h>

#define FLAT 12288
#define NH   4096
#define KSTEPS 4
#define LRC 0.01f
#define NSEG 384
#define RPS  32        // NSEG * RPS == FLAT  (pass-0 split)
#define NSEG2 768      // fused kernel: 192 blocks x 4 waves
#define WSCALE 64.0f
#define WINV   0.015625f

typedef float v2f __attribute__((ext_vector_type(2)));

__device__ __forceinline__ float sigm(float x) {
    return __builtin_amdgcn_rcpf(1.0f + __expf(-x));
}

// ---- DPP wave64 sum: result valid in lane 63 ----
template <int CTRL>
__device__ __forceinline__ float dpp_add(float x) {
    int s = __builtin_amdgcn_update_dpp(0, __float_as_int(x), CTRL, 0xf, 0xf, true);
    return x + __int_as_float(s);
}
__device__ __forceinline__ float wave_sum63(float x) {
    x = dpp_add<0x111>(x);  // row_shr:1
    x = dpp_add<0x112>(x);  // row_shr:2
    x = dpp_add<0x114>(x);  // row_shr:4
    x = dpp_add<0x118>(x);  // row_shr:8
    x = dpp_add<0x142>(x);  // row_bcast:15
    x = dpp_add<0x143>(x);  // row_bcast:31
    return x;               // lane 63 holds the full sum
}

// ================= Phase A =================

// Pass 0: read fp32 W, emit column partials for h1, convert W -> fp8 (x64).
// grid (4, NSEG), block 256; 4 cols/thread.
__global__ __launch_bounds__(256) void k_colpart_cvt(const float* __restrict__ W,
                                                     const float* __restrict__ v,
                                                     float* __restrict__ partials,
                                                     unsigned int* __restrict__ W8) {
    const float4* W4 = (const float4*)W;
    int c4 = blockIdx.x * 256 + threadIdx.x;           // [0,1024)
    int r0 = blockIdx.y * RPS;
    float4 acc = make_float4(0.f, 0.f, 0.f, 0.f);
    for (int r = r0; r < r0 + RPS; ++r) {
        float vr = v[r];
        float4 w = W4[(size_t)r * (NH / 4) + c4];
        acc.x = fmaf(w.x, vr, acc.x);
        acc.y = fmaf(w.y, vr, acc.y);
        acc.z = fmaf(w.z, vr, acc.z);
        acc.w = fmaf(w.w, vr, acc.w);
        unsigned int p = 0;
        p = __builtin_amdgcn_cvt_pk_fp8_f32(w.x * WSCALE, w.y * WSCALE, p, false);
        p = __builtin_amdgcn_cvt_pk_fp8_f32(w.z * WSCALE, w.w * WSCALE, p, true);
        W8[(size_t)r * (NH / 4) + c4] = p;
    }
    ((float4*)partials)[(size_t)blockIdx.y * (NH / 4) + c4] = acc;
}

// h[col] = sigm(b + sum over nseg partials). grid NH/32, block 256 (32 cols x 8 seg-threads).
__global__ __launch_bounds__(256) void k_hreduce(const float* __restrict__ partials,
                                                 const float* __restrict__ b,
                                                 float* __restrict__ h,
                                                 float* __restrict__ hi,
                                                 int nseg) {
    int c  = threadIdx.x & 31;
    int sg = threadIdx.x >> 5;                          // 0..7
    int col = blockIdx.x * 32 + c;
    float s = 0.f;
    for (int g = sg; g < nseg; g += 8) s += partials[(size_t)g * NH + col];
    __shared__ float red[8][33];
    red[sg][c] = s;
    __syncthreads();
    if (threadIdx.x < 32) {
        float t = 0.f;
#pragma unroll
        for (int g2 = 0; g2 < 8; g2++) t += red[g2][threadIdx.x];
        float hh = sigm(t + b[col]);
        h[col] = hh;
        if (hi) hi[col] = hh;
    }
}

// Fused: v[r] = sigm(a + W8[r,:].h/64)  AND  partials[seg][c] += W8[r][c]*v[r]/64
// for the NEXT h. One wave handles 16 rows; block = 4 waves = 64 rows.
// grid FLAT/64 = 192 blocks, block 256. Per-wave partials -> global (seg = blk*4+wave).
__global__ __launch_bounds__(256, 1) void k_fused(const unsigned char* __restrict__ W8,
                                                  const float* __restrict__ h,
                                                  const float* __restrict__ a,
                                                  float* __restrict__ v,
                                                  float* __restrict__ partials) {
    int lane = threadIdx.x & 63, wv = threadIdx.x >> 6;
    int rbase = blockIdx.x * 64 + wv * 16;
    const float4* h4 = (const float4*)h;

    // preload this lane's h fragment: chunks k = lane + 64j, j=0..3; 16 floats each
    float4 hreg[16];
#pragma unroll
    for (int j = 0; j < 4; j++) {
        int k = lane + 64 * j;
#pragma unroll
        for (int q = 0; q < 4; q++) hreg[4 * j + q] = h4[4 * k + q];
    }

    float pacc[64];
#pragma unroll
    for (int i = 0; i < 64; i++) pacc[i] = 0.f;

    for (int i = 0; i < 16; ++i) {
        int r = rbase + i;
        const uint4* Wr = (const uint4*)(W8 + (size_t)r * NH);
        uint4 wq[4];
#pragma unroll
        for (int j = 0; j < 4; j++) wq[j] = Wr[lane + 64 * j];

        float dot = 0.f;
#pragma unroll
        for (int j = 0; j < 4; j++) {
            v2f f;
            f = __builtin_amdgcn_cvt_pk_f32_fp8(wq[j].x, false); dot = fmaf(f.x, hreg[4*j].x, dot);   dot = fmaf(f.y, hreg[4*j].y, dot);
            f = __builtin_amdgcn_cvt_pk_f32_fp8(wq[j].x, true);  dot = fmaf(f.x, hreg[4*j].z, dot);   dot = fmaf(f.y, hreg[4*j].w, dot);
            f = __builtin_amdgcn_cvt_pk_f32_fp8(wq[j].y, false); dot = fmaf(f.x, hreg[4*j+1].x, dot); dot = fmaf(f.y, hreg[4*j+1].y, dot);
            f = __builtin_amdgcn_cvt_pk_f32_fp8(wq[j].y, true);  dot = fmaf(f.x, hreg[4*j+1].z, dot); dot = fmaf(f.y, hreg[4*j+1].w, dot);
            f = __builtin_amdgcn_cvt_pk_f32_fp8(wq[j].z, false); dot = fmaf(f.x, hreg[4*j+2].x, dot); dot = fmaf(f.y, hreg[4*j+2].y, dot);
            f = __builtin_amdgcn_cvt_pk_f32_fp8(wq[j].z, true);  dot = fmaf(f.x, hreg[4*j+2].z, dot); dot = fmaf(f.y, hreg[4*j+2].w, dot);
            f = __builtin_amdgcn_cvt_pk_f32_fp8(wq[j].w, false); dot = fmaf(f.x, hreg[4*j+3].x, dot); dot = fmaf(f.y, hreg[4*j+3].y, dot);
            f = __builtin_amdgcn_cvt_pk_f32_fp8(wq[j].w, true);  dot = fmaf(f.x, hreg[4*j+3].z, dot); dot = fmaf(f.y, hreg[4*j+3].w, dot);
        }
        dot = wave_sum63(dot);
        float full = __shfl(dot, 63);
        float vr = sigm(a[r] + full * WINV);
        if (lane == 63) v[r] = vr;

        // rank-1 accumulate with the W fragment still in registers (re-unpack)
        float vs = vr * WINV;     // fold descale once
#pragma unroll
        for (int j = 0; j < 4; j++) {
            v2f f;
            f = __builtin_amdgcn_cvt_pk_f32_fp8(wq[j].x, false); pacc[16*j+0]  = fmaf(f.x, vs, pacc[16*j+0]);  pacc[16*j+1]  = fmaf(f.y, vs, pacc[16*j+1]);
            f = __builtin_amdgcn_cvt_pk_f32_fp8(wq[j].x, true);  pacc[16*j+2]  = fmaf(f.x, vs, pacc[16*j+2]);  pacc[16*j+3]  = fmaf(f.y, vs, pacc[16*j+3]);
            f = __builtin_amdgcn_cvt_pk_f32_fp8(wq[j].y, false); pacc[16*j+4]  = fmaf(f.x, vs, pacc[16*j+4]);  pacc[16*j+5]  = fmaf(f.y, vs, pacc[16*j+5]);
            f = __builtin_amdgcn_cvt_pk_f32_fp8(wq[j].y, true);  pacc[16*j+6]  = fmaf(f.x, vs, pacc[16*j+6]);  pacc[16*j+7]  = fmaf(f.y, vs, pacc[16*j+7]);
            f = __builtin_amdgcn_cvt_pk_f32_fp8(wq[j].z, false); pacc[16*j+8]  = fmaf(f.x, vs, pacc[16*j+8]);  pacc[16*j+9]  = fmaf(f.y, vs, pacc[16*j+9]);
            f = __builtin_amdgcn_cvt_pk_f32_fp8(wq[j].z, true);  pacc[16*j+10] = fmaf(f.x, vs, pacc[16*j+10]); pacc[16*j+11] = fmaf(f.y, vs, pacc[16*j+11]);
            f = __builtin_amdgcn_cvt_pk_f32_fp8(wq[j].w, false); pacc[16*j+12] = fmaf(f.x, vs, pacc[16*j+12]); pacc[16*j+13] = fmaf(f.y, vs, pacc[16*j+13]);
            f = __builtin_amdgcn_cvt_pk_f32_fp8(wq[j].w, true);  pacc[16*j+14] = fmaf(f.x, vs, pacc[16*j+14]); pacc[16*j+15] = fmaf(f.y, vs, pacc[16*j+15]);
        }
    }

    // write this wave's partials: seg = blockIdx.x*4 + wv; cols 16*(lane+64j)+e
    float* P = partials + (size_t)(blockIdx.x * 4 + wv) * NH;
#pragma unroll
    for (int j = 0; j < 4; j++) {
        float4* Pj = (float4*)(P + 16 * (lane + 64 * j));
#pragma unroll
        for (int q = 0; q < 4; q++) {
            float4 o;
            o.x = pacc[16*j + 4*q + 0]; o.y = pacc[16*j + 4*q + 1];
            o.z = pacc[16*j + 4*q + 2]; o.w = pacc[16*j + 4*q + 3];
            Pj[q] = o;
        }
    }
}

// Final v-step only (no next-h needed). One wave per row. grid FLAT/4, block 256.
__global__ __launch_bounds__(256) void k_vstep_fp8(const unsigned char* __restrict__ W8,
                                                   const float* __restrict__ h,
                                                   const float* __restrict__ a,
                                                   float* __restrict__ v) {
    int wid = threadIdx.x >> 6, lane = threadIdx.x & 63;
    int row = blockIdx.x * 4 + wid;
    const uint4* Wr = (const uint4*)(W8 + (size_t)row * NH);
    const float4* h4 = (const float4*)h;
    float acc = 0.f;
    for (int k = lane; k < NH / 16; k += 64) {          // 4 iters
        uint4 w = Wr[k];
        float4 h0 = h4[4*k], h1 = h4[4*k+1], h2 = h4[4*k+2], h3 = h4[4*k+3];
        v2f f;
        f = __builtin_amdgcn_cvt_pk_f32_fp8(w.x, false); acc = fmaf(f.x, h0.x, acc); acc = fmaf(f.y, h0.y, acc);
        f = __builtin_amdgcn_cvt_pk_f32_fp8(w.x, true);  acc = fmaf(f.x, h0.z, acc); acc = fmaf(f.y, h0.w, acc);
        f = __builtin_amdgcn_cvt_pk_f32_fp8(w.y, false); acc = fmaf(f.x, h1.x, acc); acc = fmaf(f.y, h1.y, acc);
        f = __builtin_amdgcn_cvt_pk_f32_fp8(w.y, true);  acc = fmaf(f.x, h1.z, acc); acc = fmaf(f.y, h1.w, acc);
        f = __builtin_amdgcn_cvt_pk_f32_fp8(w.z, false); acc = fmaf(f.x, h2.x, acc); acc = fmaf(f.y, h2.y, acc);
        f = __builtin_amdgcn_cvt_pk_f32_fp8(w.z, true);  acc = fmaf(f.x, h2.z, acc); acc = fmaf(f.y, h2.w, acc);
        f = __builtin_amdgcn_cvt_pk_f32_fp8(w.w, false); acc = fmaf(f.x, h3.x, acc); acc = fmaf(f.y, h3.y, acc);
        f = __builtin_amdgcn_cvt_pk_f32_fp8(w.w, true);  acc = fmaf(f.x, h3.z, acc); acc = fmaf(f.y, h3.w, acc);
    }
    acc = wave_sum63(acc);
    if (lane == 63) v[row] = sigm(a[row] + acc * WINV);
}

// ================= Phase B (unchanged from R4) =================

#define TB  512
#define RVB (FLAT / TB)   // 24
#define RHB (NH / TB)     // 8
#define NWAVES (TB / 64)  // 8

__global__ __launch_bounds__(512) void k_phaseB(const float* __restrict__ inputs,
                                                const float* __restrict__ hi0,
                                                const float* __restrict__ hk0,
                                                const float* __restrict__ vk0,
                                                float* __restrict__ out) {
    int t = threadIdx.x;
    int lane = t & 63, wid = t >> 6;
    __shared__ float2 red[2][NWAVES];

    float Vi[RVB], Vk[RVB], v[RVB];
    float Hi[RHB], Hk[RHB], h[RHB], hini[RHB];

#pragma unroll
    for (int r = 0; r < RVB; r++) { int i = r * TB + t; Vi[r] = inputs[i]; Vk[r] = vk0[i]; }
#pragma unroll
    for (int r = 0; r < RHB; r++) { int j = r * TB + t; Hi[r] = hi0[j]; Hk[r] = hk0[j]; }

    int rc = 0;
    for (int s = 1; s < 16; ++s) {
        const float* vin = inputs + (size_t)s * FLAT;
#pragma unroll
        for (int r = 0; r < RVB; r++) v[r] = vin[r * TB + t];

        for (int k = 0; k < KSTEPS; ++k) {
            float px0 = 0.f, px1 = 0.f, py0 = 0.f, py1 = 0.f;
#pragma unroll
            for (int r = 0; r < RVB; r += 2) {
                px0 = fmaf(Vi[r],   v[r],   px0); py0 = fmaf(Vk[r],   v[r],   py0);
                px1 = fmaf(Vi[r+1], v[r+1], px1); py1 = fmaf(Vk[r+1], v[r+1], py1);
            }
            float px = wave_sum63(px0 + px1), py = wave_sum63(py0 + py1);
            if (lane == 63) { float2 w2; w2.x = px; w2.y = py; red[rc & 1][wid] = w2; }
            __syncthreads();
            float al = 0.f, be = 0.f;
#pragma unroll
            for (int w = 0; w < NWAVES; w++) { float2 w2 = red[rc & 1][w]; al += w2.x; be += w2.y; }
            rc++;
            float ca = LRC * (1.f + al), cb = LRC * (1.f + be);

            float qx = 0.f, qy = 0.f;
#pragma unroll
            for (int r = 0; r < RHB; r++) {
                float hh = sigm(ca * Hi[r] - cb * Hk[r]);
                h[r] = hh;
                if (k == 0) hini[r] = hh;
                qx = fmaf(Hi[r], hh, qx); qy = fmaf(Hk[r], hh, qy);
            }
            qx = wave_sum63(qx); qy = wave_sum63(qy);
            if (lane == 63) { float2 w2; w2.x = qx; w2.y = qy; red[rc & 1][wid] = w2; }
            __syncthreads();
            float ga = 0.f, de = 0.f;
#pragma unroll
            for (int w = 0; w < NWAVES; w++) { float2 w2 = red[rc & 1][w]; ga += w2.x; de += w2.y; }
            rc++;
            float cg = LRC * (1.f + ga), cd = LRC * (1.f + de);

#pragma unroll
            for (int r = 0; r < RVB; r++) v[r] = sigm(cg * Vi[r] - cd * Vk[r]);
        }

#pragma unroll
        for (int r = 0; r < RVB; r++) { Vk[r] = v[r]; Vi[r] = vin[r * TB + t]; }
#pragma unroll
        for (int r = 0; r < RHB; r++) { Hk[r] = h[r]; Hi[r] = hini[r]; }
    }

#pragma unroll
    for (int r = 0; r < RVB; r++) out[r * TB + t] = Vk[r];
}

// ================= launch =================

extern "C" void kernel_launch(void* const* d_in, const int* in_sizes, int n_in,
                              void* d_out, int out_size, void* d_ws, size_t ws_size,
                              hipStream_t stream) {
    const float* inputs = (const float*)d_in[0];
    const float* W      = (const float*)d_in[1];
    const float* a_in   = (const float*)d_in[2];
    const float* b_in   = (const float*)d_in[3];
    float* out = (float*)d_out;

    // ws layout: W8 (48 MiB) | partials (NSEG2*NH = 12 MiB) | h | hi | v
    unsigned int* W8 = (unsigned int*)d_ws;
    float* partials = (float*)((char*)d_ws + (size_t)FLAT * NH);
    float* h  = partials + (size_t)NSEG2 * NH;
    float* hi = h + NH;
    float* v  = hi + NH;

    dim3 blk(256);

    // h1 (= h_init) from fp32 W, converting W -> fp8 on the way
    k_colpart_cvt<<<dim3(4, NSEG), blk, 0, stream>>>(W, inputs, partials, W8);
    k_hreduce<<<dim3(NH / 32), blk, 0, stream>>>(partials, b_in, h, hi, NSEG);

    // steps: v1..v3 fused with partials for h2..h4
    for (int k = 1; k < KSTEPS; ++k) {
        k_fused<<<dim3(FLAT / 64), blk, 0, stream>>>((const unsigned char*)W8, h, a_in, v, partials);
        k_hreduce<<<dim3(NH / 32), blk, 0, stream>>>(partials, b_in, h, (float*)nullptr, NSEG2);
    }
    // final v4
    k_vstep_fp8<<<dim3(FLAT / 4), blk, 0, stream>>>((const unsigned char*)W8, h, a_in, v);

    // Samples 1..15 (rank-2 W), writes final reconstruction
    k_phaseB<<<1, TB, 0, stream>>>(inputs, hi, h, v, out);
}